// Round 3
// baseline (264.000 us; speedup 1.0000x reference)
//
#include <hip/hip_runtime.h>
#include <hip/hip_bf16.h>
#include <math.h>

#define NPTS   16384
#define NCH    8
#define HID    256
#define MT     64
#define LSTR   264   // LDS activation row stride (256 + 8 pad) in bf16 elems
#define MAXTB  264   // max total row-tiles: N/64 + 8 charts of padding

typedef short bf16x8 __attribute__((ext_vector_type(8)));
typedef float f32x4  __attribute__((ext_vector_type(4)));

__device__ __forceinline__ float bf2f(unsigned short u){
  union { unsigned int i; float f; } v; v.i = ((unsigned int)u) << 16; return v.f;
}
__device__ __forceinline__ unsigned short f2bf(float f){
  union { float f; unsigned int i; } v; v.f = f;
  unsigned int x = v.i;
  return (unsigned short)((x + 0x7fffu + ((x >> 16) & 1u)) >> 16); // RNE
}

// ---- bookkeeping kernels -------------------------------------------------

__global__ void init_k(int* counts){          // zeros counts[8] + cursors[8]
  int t = threadIdx.x;
  if (t < 16) counts[t] = 0;
}

__global__ void hist_k(const int* __restrict__ midx, int* __restrict__ counts){
  __shared__ int lc[NCH];
  if (threadIdx.x < NCH) lc[threadIdx.x] = 0;
  __syncthreads();
  int i = blockIdx.x * blockDim.x + threadIdx.x;
  if (i < NPTS) atomicAdd(&lc[midx[i]], 1);
  __syncthreads();
  if (threadIdx.x < NCH) atomicAdd(&counts[threadIdx.x], lc[threadIdx.x]);
}

__global__ void plan_k(const int* __restrict__ counts, int* __restrict__ base,
                       int* __restrict__ table){
  if (threadIdx.x == 0 && blockIdx.x == 0){
    int off = 0, nb = 0;
    for (int c = 0; c < NCH; c++){
      base[c] = off;
      int cnt = counts[c];
      int tiles = (cnt + MT - 1) / MT;
      for (int t = 0; t < tiles; t++){ table[nb*2] = c; table[nb*2+1] = t; nb++; }
      off += cnt;
    }
    for (; nb < MAXTB; nb++){ table[nb*2] = -1; table[nb*2+1] = 0; }
  }
}

__global__ void scatter_k(const int* __restrict__ midx, const int* __restrict__ base,
                          int* __restrict__ cursors, int* __restrict__ bucket){
  int i = blockIdx.x * blockDim.x + threadIdx.x;
  if (i < NPTS){
    int c = midx[i];
    int p = base[c] + atomicAdd(&cursors[c], 1);
    bucket[p] = i;
  }
}

// ---- weight transpose + fp32->bf16: Wth[c][l][n][k] = bf16(Wh[c][l][k][n])

__global__ void tr_wh_k(const float* __restrict__ Wh,
                        unsigned short* __restrict__ Wth){
  __shared__ __align__(16) float tile[64][68];
  int bid = blockIdx.x;
  int mat = bid >> 4;          // 48 matrices of 256x256
  int t4  = bid & 15;
  int kr  = (t4 >> 2) << 6;    // k tile offset
  int nc  = (t4 & 3) << 6;     // n tile offset
  const float* src = Wh + (size_t)mat * 65536;
  unsigned short* dst = Wth + (size_t)mat * 65536;
  int tid = threadIdx.x;
  int r  = tid >> 2;
  int cs = (tid & 3) << 4;
  const float* sp = &src[(kr + r) * 256 + nc + cs];
  *(float4*)&tile[r][cs]      = *(const float4*)&sp[0];
  *(float4*)&tile[r][cs + 4]  = *(const float4*)&sp[4];
  *(float4*)&tile[r][cs + 8]  = *(const float4*)&sp[8];
  *(float4*)&tile[r][cs + 12] = *(const float4*)&sp[12];
  __syncthreads();
  int n  = tid >> 2;
  int ks = (tid & 3) << 4;
  __align__(16) unsigned short tmp[16];
  #pragma unroll
  for (int j = 0; j < 16; j++) tmp[j] = f2bf(tile[ks + j][n]);
  *(uint4*)&dst[(nc + n) * 256 + kr + ks]     = *(const uint4*)&tmp[0];
  *(uint4*)&dst[(nc + n) * 256 + kr + ks + 8] = *(const uint4*)&tmp[8];
}

// Wt0[c][n][k] = bf16(W0[c][k][n]), k padded 29 -> 32 with zeros
__global__ void tr_w0_k(const float* __restrict__ W0,
                        unsigned short* __restrict__ Wt0){
  int i = blockIdx.x * blockDim.x + threadIdx.x;
  if (i >= NCH * 256 * 32) return;
  int k = i & 31;
  int n = (i >> 5) & 255;
  int c = i >> 13;
  unsigned short v = 0;
  if (k < 29) v = f2bf(W0[(c * 29 + k) * 256 + n]);
  Wt0[i] = v;
}

// ---- main fused MLP kernel -----------------------------------------------

__global__ __launch_bounds__(256) void mlp_k(
    const float* __restrict__ x,
    const float* __restrict__ proc,
    const float* __restrict__ b0,
    const float* __restrict__ bh,
    const float* __restrict__ Wl,
    const float* __restrict__ bl,
    const unsigned short* __restrict__ Wt0,
    const unsigned short* __restrict__ Wth,
    const int* __restrict__ counts,
    const int* __restrict__ base,
    const int* __restrict__ table,
    const int* __restrict__ bucket,
    float* __restrict__ out)
{
  __shared__ __align__(16) unsigned short hA[MT * LSTR];
  __shared__ __align__(16) unsigned short hB[MT * LSTR];
  __shared__ int ridx[MT];

  int chart = table[blockIdx.x * 2];
  if (chart < 0) return;
  int tile = table[blockIdx.x * 2 + 1];
  int cbase = base[chart];
  int cnt = counts[chart] - tile * MT;
  if (cnt > MT) cnt = MT;

  int tid  = threadIdx.x;
  int lane = tid & 63;
  int wv   = tid >> 6;
  int l15  = lane & 15;
  int quad = lane >> 4;

  // Phase A: gather indices, compute positional encoding into hA[row][0..31]
  if (tid < MT){
    int row = tid;
    int g = (row < cnt) ? bucket[cbase + tile * MT + row] : -1;
    ridx[row] = g;
    unsigned short* rowp = &hA[row * LSTR];
    if (g >= 0){
      float xv0 = x[g*3+0], xv1 = x[g*3+1], xv2 = x[g*3+2];
      rowp[0] = f2bf(xv0); rowp[1] = f2bf(xv1); rowp[2] = f2bf(xv2);
      #pragma unroll
      for (int d = 1; d <= 4; d++){
        float s = (float)(1 << d) * 3.14159265358979323846f;
        int o = 3 + (d - 1) * 6;
        rowp[o+0] = f2bf(sinf(s*xv0)); rowp[o+1] = f2bf(sinf(s*xv1)); rowp[o+2] = f2bf(sinf(s*xv2));
        rowp[o+3] = f2bf(cosf(s*xv0)); rowp[o+4] = f2bf(cosf(s*xv1)); rowp[o+5] = f2bf(cosf(s*xv2));
      }
      rowp[27] = f2bf(proc[0]); rowp[28] = f2bf(proc[1]);
      rowp[29] = 0; rowp[30] = 0; rowp[31] = 0;
    } else {
      #pragma unroll
      for (int k = 0; k < 32; k++) rowp[k] = 0;
    }
  }
  __syncthreads();

  int nb = wv * 64;   // this wave's output-column base
  f32x4 acc[4][4];

  // Layer 0: (64x32) @ (32x256), single K-step
  {
    const unsigned short* W0p = Wt0 + chart * (256 * 32);
    bf16x8 a[4], b[4];
    #pragma unroll
    for (int mt = 0; mt < 4; mt++)
      a[mt] = *(const bf16x8*)&hA[(mt * 16 + l15) * LSTR + quad * 8];
    #pragma unroll
    for (int nt = 0; nt < 4; nt++)
      b[nt] = *(const bf16x8*)&W0p[(nb + nt * 16 + l15) * 32 + quad * 8];
    #pragma unroll
    for (int mt = 0; mt < 4; mt++)
      #pragma unroll
      for (int nt = 0; nt < 4; nt++){
        f32x4 z = {0.f, 0.f, 0.f, 0.f};
        acc[mt][nt] = __builtin_amdgcn_mfma_f32_16x16x32_bf16(a[mt], b[nt], z, 0, 0, 0);
      }
    const float* b0c = b0 + chart * 256;
    #pragma unroll
    for (int nt = 0; nt < 4; nt++){
      int col = nb + nt * 16 + l15;
      float bias = b0c[col];
      #pragma unroll
      for (int mt = 0; mt < 4; mt++)
        #pragma unroll
        for (int r = 0; r < 4; r++){
          float v = acc[mt][nt][r] + bias;
          v = v > 0.f ? v : 0.f;
          hB[(mt * 16 + quad * 4 + r) * LSTR + col] = f2bf(v);
        }
    }
  }
  __syncthreads();

  // 6 hidden layers: (64x256) @ (256x256)
  unsigned short* hin  = hB;
  unsigned short* hout = hA;
  for (int l = 0; l < 6; l++){
    const unsigned short* Wp = Wth + (size_t)(chart * 6 + l) * 65536;
    const float* bp = bh + (chart * 6 + l) * 256;
    #pragma unroll
    for (int mt = 0; mt < 4; mt++)
      #pragma unroll
      for (int nt = 0; nt < 4; nt++)
        acc[mt][nt] = (f32x4){0.f, 0.f, 0.f, 0.f};
    #pragma unroll
    for (int kk = 0; kk < 8; kk++){
      int k0 = kk * 32;
      bf16x8 a[4], b[4];
      #pragma unroll
      for (int mt = 0; mt < 4; mt++)
        a[mt] = *(const bf16x8*)&hin[(mt * 16 + l15) * LSTR + k0 + quad * 8];
      #pragma unroll
      for (int nt = 0; nt < 4; nt++)
        b[nt] = *(const bf16x8*)&Wp[(nb + nt * 16 + l15) * 256 + k0 + quad * 8];
      #pragma unroll
      for (int nt = 0; nt < 4; nt++)
        #pragma unroll
        for (int mt = 0; mt < 4; mt++)
          acc[mt][nt] = __builtin_amdgcn_mfma_f32_16x16x32_bf16(a[mt], b[nt], acc[mt][nt], 0, 0, 0);
    }
    #pragma unroll
    for (int nt = 0; nt < 4; nt++){
      int col = nb + nt * 16 + l15;
      float bias = bp[col];
      #pragma unroll
      for (int mt = 0; mt < 4; mt++)
        #pragma unroll
        for (int r = 0; r < 4; r++){
          float v = acc[mt][nt][r] + bias;
          v = v > 0.f ? v : 0.f;
          hout[(mt * 16 + quad * 4 + r) * LSTR + col] = f2bf(v);
        }
    }
    __syncthreads();
    unsigned short* t = hin; hin = hout; hout = t;
  }

  // Final layer: (64x256) @ (256x2) + sigmoid, scatter to out (fp32!)
  {
    int m = tid >> 2;
    int p = tid & 3;
    const unsigned short* hrow = hin + m * LSTR + p * 64;
    const float* Wlp = Wl + chart * 512 + p * 128;
    float s0 = 0.f, s1 = 0.f;
    #pragma unroll 8
    for (int k = 0; k < 64; k++){
      float hv = bf2f(hrow[k]);
      s0 += hv * Wlp[k*2];
      s1 += hv * Wlp[k*2+1];
    }
    s0 += __shfl_xor(s0, 1); s0 += __shfl_xor(s0, 2);
    s1 += __shfl_xor(s1, 1); s1 += __shfl_xor(s1, 2);
    if (p == 0){
      int g = ridx[m];
      if (g >= 0){
        float o0 = 1.f / (1.f + __expf(-(s0 + bl[chart*2+0])));
        float o1 = 1.f / (1.f + __expf(-(s1 + bl[chart*2+1])));
        float2 o = make_float2(o0, o1);
        *(float2*)&out[(size_t)g * 2] = o;
      }
    }
  }
}

// ---- launch ---------------------------------------------------------------

extern "C" void kernel_launch(void* const* d_in, const int* in_sizes, int n_in,
                              void* d_out, int out_size, void* d_ws, size_t ws_size,
                              hipStream_t stream){
  const float* x    = (const float*)d_in[0];
  const float* proc = (const float*)d_in[1];
  const float* W0   = (const float*)d_in[2];
  const float* b0   = (const float*)d_in[3];
  const float* Wh   = (const float*)d_in[4];
  const float* bh   = (const float*)d_in[5];
  const float* Wl   = (const float*)d_in[6];
  const float* bl   = (const float*)d_in[7];
  const int* midx = (const int*)d_in[8];
  float* out = (float*)d_out;

  char* ws = (char*)d_ws;
  int* counts  = (int*)ws;                    // 8 ints
  int* cursors = counts + 8;                  // 8 ints
  int* base    = counts + 16;                 // 8 ints
  int* table   = counts + 24;                 // MAXTB*2 ints
  int* bucket  = table + 2 * MAXTB;           // NPTS ints
  size_t off = (((size_t)(24 + 2 * MAXTB + NPTS)) * 4 + 15) & ~(size_t)15;
  unsigned short* Wt0 = (unsigned short*)(ws + off);          // 8*256*32 bf16
  unsigned short* Wth = Wt0 + NCH * 256 * 32;                 // 8*6*256*256 bf16

  hipLaunchKernelGGL(init_k,    dim3(1),            dim3(64),  0, stream, counts);
  hipLaunchKernelGGL(hist_k,    dim3(NPTS/256),     dim3(256), 0, stream, midx, counts);
  hipLaunchKernelGGL(plan_k,    dim3(1),            dim3(64),  0, stream, counts, base, table);
  hipLaunchKernelGGL(scatter_k, dim3(NPTS/256),     dim3(256), 0, stream, midx, base, cursors, bucket);
  hipLaunchKernelGGL(tr_wh_k,   dim3(48*16),        dim3(256), 0, stream, Wh, Wth);
  hipLaunchKernelGGL(tr_w0_k,   dim3(NCH*256*32/256), dim3(256), 0, stream, W0, Wt0);
  hipLaunchKernelGGL(mlp_k,     dim3(MAXTB),        dim3(256), 0, stream,
                     x, proc, b0, bh, Wl, bl, Wt0, Wth, counts, base, table, bucket, out);
}

// Round 4
// 213.143 us; speedup vs baseline: 1.2386x; 1.2386x over previous
//
#include <hip/hip_runtime.h>
#include <hip/hip_bf16.h>
#include <math.h>

#define NPTS   16384
#define NCH    8
#define HID    256
#define MT     16    // rows per block (small tile -> high occupancy)
#define LSTR   264   // LDS activation row stride (256 + 8 pad) in bf16 elems
#define MAXTB  1032  // max total row-tiles: N/16 + 8 charts of padding

typedef short bf16x8 __attribute__((ext_vector_type(8)));
typedef float f32x4  __attribute__((ext_vector_type(4)));

__device__ __forceinline__ float bf2f(unsigned short u){
  union { unsigned int i; float f; } v; v.i = ((unsigned int)u) << 16; return v.f;
}
__device__ __forceinline__ unsigned short f2bf(float f){
  union { float f; unsigned int i; } v; v.f = f;
  unsigned int x = v.i;
  return (unsigned short)((x + 0x7fffu + ((x >> 16) & 1u)) >> 16); // RNE
}

// ---- one-kernel bookkeeping: hist + prefix + table + scatter (all in LDS) --

__global__ __launch_bounds__(1024) void prep_k(const int* __restrict__ midx,
    int* __restrict__ counts, int* __restrict__ base,
    int* __restrict__ table, int* __restrict__ bucket){
  __shared__ int h[NCH], bs[NCH], cur[NCH], tb[NCH], tn[NCH];
  int tid = threadIdx.x;
  if (tid < NCH) h[tid] = 0;
  __syncthreads();
  for (int i = tid; i < NPTS; i += 1024) atomicAdd(&h[midx[i]], 1);
  __syncthreads();
  if (tid == 0){
    int off = 0, toff = 0;
    for (int c = 0; c < NCH; c++){
      bs[c] = off; off += h[c];
      tb[c] = toff; tn[c] = (h[c] + MT - 1) / MT; toff += tn[c];
    }
  }
  __syncthreads();
  if (tid < NCH){ counts[tid] = h[tid]; base[tid] = bs[tid]; cur[tid] = 0; }
  __syncthreads();
  for (int t = tid; t < MAXTB; t += 1024){
    int c = -1, tt = 0;
    #pragma unroll
    for (int cc = 0; cc < NCH; cc++){
      if (t >= tb[cc] && t < tb[cc] + tn[cc]){ c = cc; tt = t - tb[cc]; }
    }
    table[2*t] = c; table[2*t+1] = tt;
  }
  for (int i = tid; i < NPTS; i += 1024){
    int c = midx[i];
    int p = bs[c] + atomicAdd(&cur[c], 1);
    bucket[p] = i;
  }
}

// ---- merged weight transpose + fp32->bf16 ---------------------------------
// blocks 0..767:  Wth[c][l][n][k] = bf16(Wh[c][l][k][n])   (48 mats x 16 tiles)
// blocks 768..775: Wt0[c][n][k]   = bf16(W0[c][k][n]), k padded 29->32

__global__ void tr_k(const float* __restrict__ Wh, const float* __restrict__ W0,
                     unsigned short* __restrict__ Wth, unsigned short* __restrict__ Wt0){
  int bid = blockIdx.x;
  int tid = threadIdx.x;
  if (bid < 768){
    __shared__ __align__(16) float tile[64][68];
    int mat = bid >> 4;
    int t4  = bid & 15;
    int kr  = (t4 >> 2) << 6;
    int nc  = (t4 & 3) << 6;
    const float* src = Wh + (size_t)mat * 65536;
    unsigned short* dst = Wth + (size_t)mat * 65536;
    int r  = tid >> 2;
    int cs = (tid & 3) << 4;
    const float* sp = &src[(kr + r) * 256 + nc + cs];
    *(float4*)&tile[r][cs]      = *(const float4*)&sp[0];
    *(float4*)&tile[r][cs + 4]  = *(const float4*)&sp[4];
    *(float4*)&tile[r][cs + 8]  = *(const float4*)&sp[8];
    *(float4*)&tile[r][cs + 12] = *(const float4*)&sp[12];
    __syncthreads();
    int n  = tid >> 2;
    int ks = (tid & 3) << 4;
    __align__(16) unsigned short tmp[16];
    #pragma unroll
    for (int j = 0; j < 16; j++) tmp[j] = f2bf(tile[ks + j][n]);
    *(uint4*)&dst[(nc + n) * 256 + kr + ks]     = *(const uint4*)&tmp[0];
    *(uint4*)&dst[(nc + n) * 256 + kr + ks + 8] = *(const uint4*)&tmp[8];
  } else {
    int c = bid - 768;
    for (int j = 0; j < 32; j++){
      int i = j * 256 + tid;          // 8192 elems: n = i>>5, k = i&31
      int k = i & 31, n = i >> 5;
      unsigned short v = 0;
      if (k < 29) v = f2bf(W0[(c * 29 + k) * 256 + n]);
      Wt0[c * 8192 + i] = v;
    }
  }
}

// ---- main fused MLP kernel (16-row tiles, 4 waves = 4 column slabs) -------

__global__ __launch_bounds__(256, 4) void mlp_k(
    const float* __restrict__ x,
    const float* __restrict__ proc,
    const float* __restrict__ b0,
    const float* __restrict__ bh,
    const float* __restrict__ Wl,
    const float* __restrict__ bl,
    const unsigned short* __restrict__ Wt0,
    const unsigned short* __restrict__ Wth,
    const int* __restrict__ counts,
    const int* __restrict__ base,
    const int* __restrict__ table,
    const int* __restrict__ bucket,
    float* __restrict__ out)
{
  __shared__ __align__(16) unsigned short hA[MT * LSTR];
  __shared__ __align__(16) unsigned short hB[MT * LSTR];
  __shared__ int ridx[MT];

  int chart = table[blockIdx.x * 2];
  if (chart < 0) return;
  int tile = table[blockIdx.x * 2 + 1];
  int cbase = base[chart];
  int cnt = counts[chart] - tile * MT;
  if (cnt > MT) cnt = MT;

  int tid  = threadIdx.x;
  int lane = tid & 63;
  int wv   = tid >> 6;
  int l15  = lane & 15;
  int quad = lane >> 4;

  // Phase A: gather + positional encoding into hA[row][0..31]
  if (tid < MT){
    int row = tid;
    int g = (row < cnt) ? bucket[cbase + tile * MT + row] : -1;
    ridx[row] = g;
    unsigned short* rowp = &hA[row * LSTR];
    if (g >= 0){
      float xv0 = x[g*3+0], xv1 = x[g*3+1], xv2 = x[g*3+2];
      rowp[0] = f2bf(xv0); rowp[1] = f2bf(xv1); rowp[2] = f2bf(xv2);
      #pragma unroll
      for (int d = 1; d <= 4; d++){
        float s = (float)(1 << d) * 3.14159265358979323846f;
        int o = 3 + (d - 1) * 6;
        rowp[o+0] = f2bf(sinf(s*xv0)); rowp[o+1] = f2bf(sinf(s*xv1)); rowp[o+2] = f2bf(sinf(s*xv2));
        rowp[o+3] = f2bf(cosf(s*xv0)); rowp[o+4] = f2bf(cosf(s*xv1)); rowp[o+5] = f2bf(cosf(s*xv2));
      }
      rowp[27] = f2bf(proc[0]); rowp[28] = f2bf(proc[1]);
      rowp[29] = 0; rowp[30] = 0; rowp[31] = 0;
    } else {
      #pragma unroll
      for (int k = 0; k < 32; k++) rowp[k] = 0;
    }
  }
  __syncthreads();

  int nb = wv * 64;   // this wave's output-column base
  f32x4 acc[4];

  // Layer 0: (16x32) @ (32x256), single K-step
  {
    const unsigned short* W0p = Wt0 + chart * 8192;
    bf16x8 a = *(const bf16x8*)&hA[l15 * LSTR + quad * 8];
    #pragma unroll
    for (int nt = 0; nt < 4; nt++){
      bf16x8 b = *(const bf16x8*)&W0p[(nb + nt * 16 + l15) * 32 + quad * 8];
      f32x4 z = {0.f, 0.f, 0.f, 0.f};
      acc[nt] = __builtin_amdgcn_mfma_f32_16x16x32_bf16(a, b, z, 0, 0, 0);
    }
    const float* b0c = b0 + chart * 256;
    #pragma unroll
    for (int nt = 0; nt < 4; nt++){
      int col = nb + nt * 16 + l15;
      float bias = b0c[col];
      #pragma unroll
      for (int r = 0; r < 4; r++){
        float v = acc[nt][r] + bias;
        v = v > 0.f ? v : 0.f;
        hB[(quad * 4 + r) * LSTR + col] = f2bf(v);
      }
    }
  }
  __syncthreads();

  // 6 hidden layers: (16x256) @ (256x256)
  unsigned short* hin  = hB;
  unsigned short* hout = hA;
  for (int l = 0; l < 6; l++){
    const unsigned short* Wp = Wth + (size_t)(chart * 6 + l) * 65536;
    const float* bp = bh + (chart * 6 + l) * 256;
    #pragma unroll
    for (int nt = 0; nt < 4; nt++) acc[nt] = (f32x4){0.f, 0.f, 0.f, 0.f};
    #pragma unroll
    for (int kk = 0; kk < 8; kk++){
      int k0 = kk * 32;
      bf16x8 a = *(const bf16x8*)&hin[l15 * LSTR + k0 + quad * 8];
      #pragma unroll
      for (int nt = 0; nt < 4; nt++){
        bf16x8 b = *(const bf16x8*)&Wp[(nb + nt * 16 + l15) * 256 + k0 + quad * 8];
        acc[nt] = __builtin_amdgcn_mfma_f32_16x16x32_bf16(a, b, acc[nt], 0, 0, 0);
      }
    }
    #pragma unroll
    for (int nt = 0; nt < 4; nt++){
      int col = nb + nt * 16 + l15;
      float bias = bp[col];
      #pragma unroll
      for (int r = 0; r < 4; r++){
        float v = acc[nt][r] + bias;
        v = v > 0.f ? v : 0.f;
        hout[(quad * 4 + r) * LSTR + col] = f2bf(v);
      }
    }
    __syncthreads();
    unsigned short* t = hin; hin = hout; hout = t;
  }

  // Final layer: (16x256) @ (256x2) + sigmoid, scatter to out (fp32)
  {
    int m = tid >> 4;          // 0..15 rows
    int p = tid & 15;          // 16 threads per row, 16 k-elems each
    const unsigned short* hrow = hin + m * LSTR + p * 16;
    const float* Wlp = Wl + chart * 512 + p * 32;
    float s0 = 0.f, s1 = 0.f;
    #pragma unroll
    for (int k = 0; k < 16; k++){
      float hv = bf2f(hrow[k]);
      s0 += hv * Wlp[k*2];
      s1 += hv * Wlp[k*2+1];
    }
    s0 += __shfl_xor(s0, 1); s0 += __shfl_xor(s0, 2);
    s0 += __shfl_xor(s0, 4); s0 += __shfl_xor(s0, 8);
    s1 += __shfl_xor(s1, 1); s1 += __shfl_xor(s1, 2);
    s1 += __shfl_xor(s1, 4); s1 += __shfl_xor(s1, 8);
    if (p == 0){
      int g = ridx[m];
      if (g >= 0){
        float o0 = 1.f / (1.f + __expf(-(s0 + bl[chart*2+0])));
        float o1 = 1.f / (1.f + __expf(-(s1 + bl[chart*2+1])));
        *(float2*)&out[(size_t)g * 2] = make_float2(o0, o1);
      }
    }
  }
}

// ---- launch ---------------------------------------------------------------

extern "C" void kernel_launch(void* const* d_in, const int* in_sizes, int n_in,
                              void* d_out, int out_size, void* d_ws, size_t ws_size,
                              hipStream_t stream){
  const float* x    = (const float*)d_in[0];
  const float* proc = (const float*)d_in[1];
  const float* W0   = (const float*)d_in[2];
  const float* b0   = (const float*)d_in[3];
  const float* Wh   = (const float*)d_in[4];
  const float* bh   = (const float*)d_in[5];
  const float* Wl   = (const float*)d_in[6];
  const float* bl   = (const float*)d_in[7];
  const int* midx = (const int*)d_in[8];
  float* out = (float*)d_out;

  char* ws = (char*)d_ws;
  int* counts  = (int*)ws;                    // 8 ints
  int* base    = counts + 8;                  // 8 ints
  int* table   = counts + 16;                 // MAXTB*2 ints
  int* bucket  = table + 2 * MAXTB;           // NPTS ints
  size_t off = (((size_t)(16 + 2 * MAXTB + NPTS)) * 4 + 15) & ~(size_t)15;
  unsigned short* Wt0 = (unsigned short*)(ws + off);          // 8*256*32 bf16
  unsigned short* Wth = Wt0 + NCH * 8192;                     // 8*6*256*256 bf16

  hipLaunchKernelGGL(prep_k, dim3(1),     dim3(1024), 0, stream, midx, counts, base, table, bucket);
  hipLaunchKernelGGL(tr_k,   dim3(776),   dim3(256),  0, stream, Wh, W0, Wth, Wt0);
  hipLaunchKernelGGL(mlp_k,  dim3(MAXTB), dim3(256),  0, stream,
                     x, proc, b0, bh, Wl, bl, Wt0, Wth, counts, base, table, bucket, out);
}